// Round 1
// baseline (421.019 us; speedup 1.0000x reference)
//
#include <hip/hip_runtime.h>
#include <hip/hip_bf16.h>

namespace {

using us = unsigned short;
typedef __attribute__((ext_vector_type(8))) short bf16x8;
typedef __attribute__((ext_vector_type(4))) float f32x4;
typedef __attribute__((ext_vector_type(4))) unsigned short us4;
typedef __attribute__((ext_vector_type(4))) unsigned int u32x4;

constexpr int DIM_ = 512, KALL = 11, DOM = 10, NPROBE = 128, NSETS = 192;
constexpr int LPR = 256, LGA = 512;

// output offsets (elements)
constexpr size_t O_OUT1 = 0;
constexpr size_t O_OUT2 = (size_t)NPROBE * 4 * DIM_;
constexpr size_t O_OUT3 = O_OUT2 + KALL * DOM;
constexpr size_t O_OUT4 = O_OUT3 + (size_t)64 * 4 * DIM_;

// workspace layout (float units). flag int at [0].
constexpr size_t F_TP   = 64;        // 256 f  normalized proxy transforms
constexpr size_t F_IDX  = 320;       // 768 i  top4 expert ids
constexpr size_t F_S0A  = 1600;      // 2112 f pb.ctx per (e,set)
constexpr size_t F_WQ   = 4096;      // [192][512][5] f32: scores k=0..3, invn at 4
constexpr size_t F_GP   = 495616;    // [1024][12] f32 gsim partials
constexpr size_t F_SUMM = 514048;    // bf16 [192][1024] mean|var
constexpr size_t F_H1   = 612352;    // bf16 [11][192][1024]
constexpr size_t F_PART = F_H1;      // [768][1024] f32 (psum|psq), dies before mlp1
constexpr size_t F_CTXW = F_H1;      // bf16 [11][192][512], after mlp2
constexpr size_t F_H2   = 1693696;   // bf16 [11][192][1024]
constexpr size_t F_ACC  = F_H2;      // [768][2048] f32, after score
constexpr size_t F_CTX  = 2775040;   // bf16 [11][192][512]
constexpr size_t F_WT   = 3315712;   // bf16 [512][512]
constexpr size_t WS_FLOATS = 3446784;
constexpr size_t WS_BYTES  = WS_FLOATS * 4;

__device__ __forceinline__ float b2f(us u) { return __uint_as_float(((unsigned)u) << 16); }
__device__ __forceinline__ us f2b(float x) {
    unsigned u = __float_as_uint(x);
    u += 0x7FFF + ((u >> 16) & 1);
    return (us)(u >> 16);
}
__device__ __forceinline__ float ldT(const float* p) { return *p; }
__device__ __forceinline__ float ldT(const us* p) { return b2f(*p); }
__device__ __forceinline__ void stT(float* p, float v) { *p = v; }
__device__ __forceinline__ void stT(us* p, float v) { *p = f2b(v); }

__device__ __forceinline__ bf16x8 loadA(const us* p) { return *(const bf16x8*)p; }
__device__ __forceinline__ bf16x8 loadA(const float* p) {
    f32x4 a = *(const f32x4*)p, b = *(const f32x4*)(p + 4);
    bf16x8 r;
#pragma unroll
    for (int j = 0; j < 4; ++j) { r[j] = (short)f2b(a[j]); r[4 + j] = (short)f2b(b[j]); }
    return r;
}

__device__ __forceinline__ void gload_lds16(const us* g, us* l) {
    __builtin_amdgcn_global_load_lds(
        (const __attribute__((address_space(1))) void*)g,
        (__attribute__((address_space(3))) void*)l, 16, 0, 0);
}

// decode 64-row-chunk grid (1024 blocks): probe 128x4, gallery 64x8
__device__ __forceinline__ void decode64(int bx, int& set, int& base, int& L) {
    if (bx < 512) { set = bx >> 2; base = (bx & 3) * 64; L = LPR; }
    else { set = NPROBE + ((bx - 512) >> 3); base = ((bx - 512) & 7) * 64; L = LGA; }
}

// ---------------- dtype detector ----------------
__global__ void detect_kernel(const unsigned int* probeW_bits, int* flag) {
    if (threadIdx.x == 0) *flag = (probeW_bits[0] == 0x3F800000u) ? 0 : 1;
}

// ---------------- proxies: out2/out4 + normalized tp ----------------
template <typename T>
__device__ void proxies_body(const T* pp, const T* pg, const T* tW, const T* tb,
                             float* wsf, T* dout) {
    int b = blockIdx.x;
    int fam = b / KALL, i = b % KALL;
    int lane = threadIdx.x;
    const T* src = fam ? pg : pp;
    float t[DOM];
#pragma unroll
    for (int r = 0; r < DOM; ++r) t[r] = 0.f;
    for (int d = lane; d < DIM_; d += 64) {
        float x = ldT(src + (size_t)i * DIM_ + d);
#pragma unroll
        for (int r = 0; r < DOM; ++r) t[r] += x * ldT(tW + (size_t)r * DIM_ + d);
    }
#pragma unroll
    for (int off = 32; off >= 1; off >>= 1)
#pragma unroll
        for (int r = 0; r < DOM; ++r) t[r] += __shfl_xor(t[r], off, 64);
#pragma unroll
    for (int r = 0; r < DOM; ++r) t[r] += ldT(tb + r);
    float nn = 0.f;
#pragma unroll
    for (int r = 0; r < DOM; ++r) nn += t[r] * t[r];
    float inv = 1.0f / fmaxf(sqrtf(nn), 1e-12f);
    if (lane < DOM) {
        size_t base = fam ? O_OUT4 : O_OUT2;
        stT(dout + base + i * DOM + lane, t[lane]);
        wsf[F_TP + fam * 128 + i * DOM + lane] = t[lane] * inv;
    }
}
__global__ void proxies_kernel(const int* flag, const void* pp, const void* pg,
                               const void* tW, const void* tb, float* wsf, void* dout) {
    if (*flag)
        proxies_body<us>((const us*)pp, (const us*)pg, (const us*)tW, (const us*)tb, wsf, (us*)dout);
    else
        proxies_body<float>((const float*)pp, (const float*)pg, (const float*)tW, (const float*)tb, wsf, (float*)dout);
}

// ---------------- pass A: per-dim sums/sumsq + per-row invn ----------------
template <typename T>
__device__ void sums_body(const T* probes, const T* gallery, const int* plen,
                          const int* glen, float* wsf) {
    int bx = blockIdx.x, set = bx >> 2, c = bx & 3;
    bool probe = set < NPROBE;
    int L = probe ? LPR : LGA;
    const T* feat = probe ? probes + (size_t)set * L * DIM_
                          : gallery + (size_t)(set - NPROBE) * L * DIM_;
    int len = probe ? plen[set] : glen[set - NPROBE];
    int len_eff = min(max(len, 1), L);
    int r0 = c * (L / 4), r1 = min(r0 + L / 4, len_eff);
    __shared__ float psum[DIM_], psq[DIM_];
    int tid = threadIdx.x, w = tid >> 6, lane = tid & 63;
    psum[tid] = 0.f; psum[tid + 256] = 0.f;
    psq[tid] = 0.f; psq[tid + 256] = 0.f;
    __syncthreads();
    float asum[8] = {0,0,0,0,0,0,0,0}, asq[8] = {0,0,0,0,0,0,0,0};
    float* wq = wsf + F_WQ + (size_t)set * 2560;
    for (int l = r0 + w * 2; l < r1; l += 8) {
        bool two = (l + 1 < r1);
        float f0[8], f1[8];
        if constexpr (sizeof(T) == 2) {
            u32x4 ra = *(const u32x4*)(feat + (size_t)l * DIM_ + lane * 8);
            u32x4 rb = two ? *(const u32x4*)(feat + (size_t)(l + 1) * DIM_ + lane * 8)
                           : (u32x4){0, 0, 0, 0};
#pragma unroll
            for (int q = 0; q < 4; ++q) {
                f0[2*q] = __uint_as_float(ra[q] << 16);
                f0[2*q+1] = __uint_as_float(ra[q] & 0xFFFF0000u);
                f1[2*q] = __uint_as_float(rb[q] << 16);
                f1[2*q+1] = __uint_as_float(rb[q] & 0xFFFF0000u);
            }
        } else {
            const T* rp = feat + (size_t)l * DIM_ + lane * 8;
            f32x4 a0 = *(const f32x4*)rp, a1 = *(const f32x4*)(rp + 4);
#pragma unroll
            for (int j = 0; j < 4; ++j) { f0[j] = a0[j]; f0[4+j] = a1[j]; }
            if (two) {
                const T* rq = feat + (size_t)(l + 1) * DIM_ + lane * 8;
                f32x4 b0 = *(const f32x4*)rq, b1 = *(const f32x4*)(rq + 4);
#pragma unroll
                for (int j = 0; j < 4; ++j) { f1[j] = b0[j]; f1[4+j] = b1[j]; }
            } else {
#pragma unroll
                for (int j = 0; j < 8; ++j) f1[j] = 0.f;
            }
        }
        float s0 = 0.f, s1 = 0.f;
#pragma unroll
        for (int j = 0; j < 8; ++j) {
            asum[j] += f0[j] + f1[j];
            asq[j] += f0[j] * f0[j] + f1[j] * f1[j];
            s0 += f0[j] * f0[j];
            s1 += f1[j] * f1[j];
        }
#pragma unroll
        for (int off = 32; off >= 1; off >>= 1) {
            s0 += __shfl_xor(s0, off, 64);
            s1 += __shfl_xor(s1, off, 64);
        }
        if (lane == 0) {
            wq[(size_t)l * 5 + 4] = 1.0f / fmaxf(sqrtf(s0), 1e-12f);
            if (two) wq[(size_t)(l + 1) * 5 + 4] = 1.0f / fmaxf(sqrtf(s1), 1e-12f);
        }
    }
#pragma unroll
    for (int j = 0; j < 8; ++j) {
        atomicAdd(&psum[lane * 8 + j], asum[j]);
        atomicAdd(&psq[lane * 8 + j], asq[j]);
    }
    __syncthreads();
    float* P = wsf + F_PART + (size_t)bx * 1024;
    P[tid] = psum[tid]; P[tid + 256] = psum[tid + 256];
    P[512 + tid] = psq[tid]; P[768 + tid] = psq[tid + 256];
}
__global__ __launch_bounds__(256) void sums_kernel(const int* flag, const void* probes,
        const void* gallery, const int* plen, const int* glen, float* wsf) {
    if (*flag) sums_body<us>((const us*)probes, (const us*)gallery, plen, glen, wsf);
    else sums_body<float>((const float*)probes, (const float*)gallery, plen, glen, wsf);
}

// ---------------- pass B: gsim via MFMA (feat @ tW^T) ----------------
template <typename T>
__device__ void sims_body(const T* probes, const T* gallery, const int* plen,
                          const int* glen, const T* tW, float* wsf) {
    int bx = blockIdx.x, set, base, L;
    decode64(bx, set, base, L);
    bool probe = set < NPROBE;
    int len = probe ? plen[set] : glen[set - NPROBE];
    int len_eff = min(max(len, 1), L);
    float* GP = wsf + F_GP + (size_t)bx * 12;
    int tid = threadIdx.x;
    if (base >= len_eff) { if (tid < KALL) GP[tid] = 0.f; return; }
    const T* feat = probe ? probes + (size_t)set * L * DIM_
                          : gallery + (size_t)(set - NPROBE) * L * DIM_;
    __shared__ __align__(16) float tile[4][320];   // [wave][16 rows][20 cols]
    __shared__ float tpl[KALL * DOM];
    __shared__ float gs[16];
    if (tid < KALL * DOM) tpl[tid] = wsf[F_TP + (probe ? 0 : 128) + tid];
    if (tid < 16) gs[tid] = 0.f;
    int w = tid >> 6, lane = tid & 63, lm = lane & 15, quad = lane >> 4;

    bf16x8 bq[16];
#pragma unroll
    for (int s = 0; s < 16; ++s) {
        if (lm < DOM) bq[s] = loadA(tW + (size_t)lm * DIM_ + s * 32 + quad * 8);
        else bq[s] = (bf16x8){0, 0, 0, 0, 0, 0, 0, 0};
    }
    int m0 = base + w * 16;
    const T* Ap = feat + (size_t)(m0 + lm) * DIM_ + quad * 8;
    f32x4 acc = (f32x4){0.f, 0.f, 0.f, 0.f};
#pragma unroll
    for (int s = 0; s < 16; ++s) {
        bf16x8 a = loadA(Ap + s * 32);
        acc = __builtin_amdgcn_mfma_f32_16x16x32_bf16(a, bq[s], acc, 0, 0, 0);
    }
#pragma unroll
    for (int r = 0; r < 4; ++r) tile[w][(quad * 4 + r) * 20 + lm] = acc[r];
    __syncthreads();

    float gacc[KALL];
#pragma unroll
    for (int k = 0; k < KALL; ++k) gacc[k] = 0.f;
    if (lane < 16) {
        int row = m0 + lane;
        if (row < len_eff) {
            const float* tr = &tile[w][lane * 20];
            f32x4 t0 = *(const f32x4*)tr, t1 = *(const f32x4*)(tr + 4);
            float tv[DOM] = {t0[0], t0[1], t0[2], t0[3], t1[0], t1[1], t1[2], t1[3], tr[8], tr[9]};
            float nn = 0.f;
#pragma unroll
            for (int r = 0; r < DOM; ++r) nn += tv[r] * tv[r];
            float inv = 1.0f / fmaxf(sqrtf(nn), 1e-12f);
#pragma unroll
            for (int k = 0; k < KALL; ++k) {
                float s = 0.f;
#pragma unroll
                for (int r = 0; r < DOM; ++r) s += tv[r] * tpl[k * DOM + r];
                gacc[k] = s * inv;
            }
        }
    }
#pragma unroll
    for (int off = 8; off >= 1; off >>= 1)
#pragma unroll
        for (int k = 0; k < KALL; ++k) gacc[k] += __shfl_xor(gacc[k], off, 64);
    if (lane == 0)
#pragma unroll
        for (int k = 0; k < KALL; ++k) atomicAdd(&gs[k], gacc[k]);
    __syncthreads();
    if (tid < KALL) GP[tid] = gs[tid];
}
__global__ __launch_bounds__(256, 3) void sims_kernel(const int* flag, const void* probes,
        const void* gallery, const int* plen, const int* glen, const void* tW, float* wsf) {
    if (*flag) sims_body<us>((const us*)probes, (const us*)gallery, plen, glen, (const us*)tW, wsf);
    else sims_body<float>((const float*)probes, (const float*)gallery, plen, glen, (const float*)tW, wsf);
}

// ---------------- finalize stats: SUMM (bf16) + top4 ----------------
__global__ void statsfin_kernel(const int* plen, const int* glen, float* wsf) {
    int set = blockIdx.x, tid = threadIdx.x;
    bool probe = set < NPROBE;
    int len = probe ? plen[set] : glen[set - NPROBE];
    float lp = (float)max(len, 1);
    const float* P = wsf + F_PART + (size_t)set * 4 * 1024;
    us* SUMM = (us*)(wsf + F_SUMM);
    for (int d = tid; d < DIM_; d += 256) {
        float s = P[d] + P[1024 + d] + P[2048 + d] + P[3072 + d];
        float q = P[512 + d] + P[1536 + d] + P[2560 + d] + P[3584 + d];
        float m = s / lp;
        float v = q / lp - m * m;
        SUMM[(size_t)set * 1024 + d] = f2b(m);
        SUMM[(size_t)set * 1024 + DIM_ + d] = f2b(v);
    }
    if (tid == 0) {
        int nch = probe ? 4 : 8;
        int gb = probe ? set * 4 : 512 + (set - NPROBE) * 8;
        float g[KALL];
        for (int i = 0; i < KALL; ++i) {
            float s = 0.f;
            for (int c = 0; c < nch; ++c) s += wsf[F_GP + (size_t)(gb + c) * 12 + i];
            g[i] = s;
        }
        int* idx4 = (int*)(wsf + F_IDX);
        for (int kk = 0; kk < 4; ++kk) {
            int bi = 0; float bv = g[0];
            for (int i = 1; i < KALL; ++i)
                if (g[i] > bv) { bv = g[i]; bi = i; }
            idx4[set * 4 + kk] = bi;
            g[bi] = -3e38f;
        }
    }
}

// ---------------- W transpose -> WT bf16 [j][d] ----------------
template <typename T>
__device__ void wt_body(const T* W, us* WT) {
    __shared__ us t[64][65];
    int bi = blockIdx.y * 64, bj = blockIdx.x * 64, tid = threadIdx.x;
    for (int i = tid; i < 4096; i += 256) {
        int r = i >> 6, cc = i & 63;
        t[r][cc] = (sizeof(T) == 2) ? ((const us*)W)[(size_t)(bi + r) * DIM_ + bj + cc]
                                    : f2b(ldT(W + (size_t)(bi + r) * DIM_ + bj + cc));
    }
    __syncthreads();
    for (int i = tid; i < 4096; i += 256) {
        int r = i >> 6, cc = i & 63;
        WT[(size_t)(bj + r) * DIM_ + bi + cc] = t[cc][r];
    }
}
__global__ void wt_kernel(const int* flag, const void* W, us* WT) {
    if (*flag) wt_body<us>((const us*)W, WT);
    else wt_body<float>((const float*)W, WT);
}

// ---------------- unified LDS-staged MFMA MLP ----------------
// fp32 weights: convert during staging (dwordx4 loads -> pack bf16 -> ds_write_b128).
// bf16 weights: async global_load_lds. Same swizzled layout + MFMA loop for both.
// XCD-aware 1D grid: blocks sharing a W m-tile differ by MT*KALL (== 0 mod 8) -> same XCD.
template <int M, int KTOT, int L1>
__global__ __launch_bounds__(256) void mlp_one(const int* flag, const void* Wv,
        const void* biasv, const void* ppv, const void* pgv, const us* X, us* Y) {
    constexpr int MT = M / 64;
    int flagv = *flag;
    __shared__ us SM[16384];
    us* As = SM;
    us* Bs = SM + 8192;
    int bx = blockIdx.x;
    int nt = bx / (MT * KALL);
    int rem = bx - nt * (MT * KALL);
    int e = rem % KALL;
    int mt = rem / KALL;
    int tid = threadIdx.x, w = tid >> 6, lane = tid & 63;
    int lm = lane & 15, quad = lane >> 4;
    const int RS = L1 ? 1024 : KTOT;
    int s0 = nt * 64;
    int srow = tid >> 4;
    int csrc = (tid & 15) ^ (srow & 7);
    us* lA = As + tid * 8;
    us* lB = Bs + tid * 8;
    const size_t arow = (size_t)e * M + mt * 64 + srow;
    const us*    AbB = (const us*)Wv + arow * KTOT + csrc * 8;
    const float* AbF = (const float*)Wv + arow * KTOT + csrc * 8;
    const us* Xbase = X + ((size_t)(L1 ? 0 : e * NSETS) + s0 + srow) * RS + csrc * 8;
    const us* PbB = nullptr;
    const float* PbF = nullptr;
    if (L1) {
        PbB = (const us*)(nt < 2 ? ppv : pgv) + (size_t)e * DIM_ + csrc * 8;
        PbF = (const float*)(nt < 2 ? ppv : pgv) + (size_t)e * DIM_ + csrc * 8;
    }
    f32x4 acc[4];
#pragma unroll
    for (int j = 0; j < 4; ++j) acc[j] = (f32x4){0.f, 0.f, 0.f, 0.f};
    int ar = w * 16 + lm, aswz = ar & 7;

    for (int k0 = 0; k0 < KTOT; k0 += 128) {
        __syncthreads();
        if (flagv) {
#pragma unroll
            for (int i = 0; i < 4; ++i)
                gload_lds16(AbB + (size_t)(i * 16) * KTOT + k0, lA + i * 2048);
        } else {
#pragma unroll
            for (int i = 0; i < 4; ++i)
                *(bf16x8*)(lA + i * 2048) = loadA(AbF + (size_t)(i * 16) * KTOT + k0);
        }
        if (!L1 || k0 < 1024) {
#pragma unroll
            for (int i = 0; i < 4; ++i)
                gload_lds16(Xbase + (size_t)(i * 16) * RS + k0, lB + i * 2048);
        } else if (flagv) {
#pragma unroll
            for (int i = 0; i < 4; ++i)
                gload_lds16(PbB + (k0 - 1024), lB + i * 2048);
        } else {
            bf16x8 v = loadA(PbF + (k0 - 1024));
#pragma unroll
            for (int i = 0; i < 4; ++i)
                *(bf16x8*)(lB + i * 2048) = v;
        }
        __syncthreads();
#pragma unroll
        for (int ks = 0; ks < 4; ++ks) {
            int cg = ks * 4 + quad;
            bf16x8 a = *(const bf16x8*)(As + ar * 128 + ((cg ^ aswz) * 8));
#pragma unroll
            for (int j = 0; j < 4; ++j) {
                int br = j * 16 + lm;
                bf16x8 b = *(const bf16x8*)(Bs + br * 128 + ((cg ^ (br & 7)) * 8));
                acc[j] = __builtin_amdgcn_mfma_f32_16x16x32_bf16(a, b, acc[j], 0, 0, 0);
            }
        }
    }
    int m0 = mt * 64 + w * 16 + quad * 4;
    float bv[4];
#pragma unroll
    for (int r = 0; r < 4; ++r)
        bv[r] = flagv ? b2f(((const us*)biasv)[(size_t)e * M + m0 + r])
                      : ((const float*)biasv)[(size_t)e * M + m0 + r];
#pragma unroll
    for (int j = 0; j < 4; ++j) {
        int s = s0 + j * 16 + lm;
        us4 pk;
#pragma unroll
        for (int r = 0; r < 4; ++r) {
            float v = acc[j][r] + bv[r];
            v = v > 0.f ? v : 0.01f * v;
            pk[r] = f2b(v);
        }
        *(us4*)(Y + ((size_t)e * NSETS + s) * M + m0) = pk;
    }
}

// ---------------- fold: CTXW = CTX @ W (probe rows) ----------------
__global__ void fold_kernel(const us* CTX, const us* WT, us* CTXW) {
    int nt = blockIdx.x, mtb = blockIdx.y;
    int e = mtb >> 1, sub = mtb & 1;
    int row0 = e * NSETS + sub * 64;
    int tid = threadIdx.x, w = tid >> 6, lane = tid & 63;
    int lm = lane & 15, quad = lane >> 4, kq = quad * 8;
    const us* Ap = CTX + ((size_t)row0 + w * 16 + lm) * DIM_ + kq;
    int n0 = nt * 64;
    const us* Bp = WT + (size_t)(n0 + lm) * DIM_ + kq;
    f32x4 acc[4];
#pragma unroll
    for (int j = 0; j < 4; ++j) acc[j] = (f32x4){0.f, 0.f, 0.f, 0.f};
#pragma unroll 2
    for (int kc = 0; kc < DIM_; kc += 32) {
        bf16x8 a = *(const bf16x8*)(Ap + kc);
#pragma unroll
        for (int j = 0; j < 4; ++j) {
            bf16x8 b = *(const bf16x8*)(Bp + kc + (size_t)j * 16 * DIM_);
            acc[j] = __builtin_amdgcn_mfma_f32_16x16x32_bf16(a, b, acc[j], 0, 0, 0);
        }
    }
    int mrow = row0 + w * 16 + quad * 4;
#pragma unroll
    for (int j = 0; j < 4; ++j)
#pragma unroll
        for (int r = 0; r < 4; ++r)
            CTXW[(size_t)(mrow + r) * DIM_ + n0 + j * 16 + lm] = f2b(acc[j][r]);
}

// ---------------- s0 = pb . ctx ----------------
template <typename T>
__device__ void s0a_body(const us* CTX, const T* pb, float* S0A) {
    int tid = threadIdx.x, w = tid >> 6, lane = tid & 63;
    int row = blockIdx.x * 4 + w;
    bf16x8 cv = *(const bf16x8*)(CTX + (size_t)row * DIM_ + lane * 8);
    float s = 0.f;
#pragma unroll
    for (int j = 0; j < 8; ++j) s += b2f((us)cv[j]) * ldT(pb + lane * 8 + j);
#pragma unroll
    for (int off = 32; off >= 1; off >>= 1) s += __shfl_xor(s, off, 64);
    if (lane == 0) S0A[row] = s;
}
__global__ void s0a_kernel(const int* flag, const us* CTX, const void* pb, float* S0A) {
    if (*flag) s0a_body<us>(CTX, (const us*)pb, S0A);
    else s0a_body<float>(CTX, (const float*)pb, S0A);
}

// ---------------- score: feat @ ctx^T via MFMA ----------------
template <typename T>
__device__ void score_body(const T* probes, const T* gallery, const int* plen,
                           const int* glen, float* wsf) {
    int bx = blockIdx.x, set, base, L;
    decode64(bx, set, base, L);
    bool probe = set < NPROBE;
    int len = probe ? plen[set] : glen[set - NPROBE];
    int len_eff = min(max(len, 1), L);
    if (base >= len_eff) return;
    const T* feat = probe ? probes + (size_t)set * L * DIM_
                          : gallery + (size_t)(set - NPROBE) * L * DIM_;
    int tid = threadIdx.x, w = tid >> 6, lane = tid & 63;
    int lm = lane & 15, quad = lane >> 4;
    const int* idx4 = (const int*)(wsf + F_IDX);
    const us* CTXW = (const us*)(wsf + F_CTXW);
    const us* CTXR = (const us*)(wsf + F_CTX);
    bf16x8 bq[16];
    float s0v = 0.f;
    if (lm < 4) {
        int row = idx4[set * 4 + lm] * NSETS + set;
        const us* src = (probe ? CTXW : CTXR) + (size_t)row * DIM_ + quad * 8;
#pragma unroll
        for (int s = 0; s < 16; ++s) bq[s] = *(const bf16x8*)(src + s * 32);
        s0v = probe ? wsf[F_S0A + row] : 0.f;
    } else {
#pragma unroll
        for (int s = 0; s < 16; ++s) bq[s] = (bf16x8){0, 0, 0, 0, 0, 0, 0, 0};
    }
    int m0 = base + w * 16;
    const T* Ap = feat + (size_t)(m0 + lm) * DIM_ + quad * 8;
    f32x4 acc = (f32x4){0.f, 0.f, 0.f, 0.f};
#pragma unroll
    for (int s = 0; s < 16; ++s) {
        bf16x8 a = loadA(Ap + s * 32);
        acc = __builtin_amdgcn_mfma_f32_16x16x32_bf16(a, bq[s], acc, 0, 0, 0);
    }
    if (lm < 4) {
        float* wq = wsf + F_WQ + (size_t)set * 2560;
#pragma unroll
        for (int r = 0; r < 4; ++r) {
            int row = m0 + quad * 4 + r;
            wq[(size_t)row * 5 + lm] = acc[r] + s0v;
        }
    }
}
__global__ __launch_bounds__(256, 3) void score_kernel(const int* flag, const void* probes,
        const void* gallery, const int* plen, const int* glen, float* wsf) {
    if (*flag) score_body<us>((const us*)probes, (const us*)gallery, plen, glen, wsf);
    else score_body<float>((const float*)probes, (const float*)gallery, plen, glen, wsf);
}

// ---------------- softmax over rows per (set,k), fold invn ----------------
__global__ void softmax_kernel(const int* plen, const int* glen, float* wsf) {
    int set = blockIdx.x, tid = threadIdx.x, k = tid >> 6, lane = tid & 63;
    bool probe = set < NPROBE;
    int L = probe ? LPR : LGA;
    int len = probe ? plen[set] : glen[set - NPROBE];
    int len_eff = min(max(len, 1), L);
    float* wq = wsf + F_WQ + (size_t)set * 2560;
    float cv[8];
    int n = 0;
    float m = -3e38f;
    for (int l = lane; l < len_eff; l += 64) {
        cv[n] = wq[(size_t)l * 5 + k];
        m = fmaxf(m, cv[n]);
        ++n;
    }
#pragma unroll
    for (int off = 32; off >= 1; off >>= 1) m = fmaxf(m, __shfl_xor(m, off, 64));
    float se = 0.f;
    for (int i = 0; i < n; ++i) se += __expf(cv[i] - m);
#pragma unroll
    for (int off = 32; off >= 1; off >>= 1) se += __shfl_xor(se, off, 64);
    float invs = 1.0f / se;
    n = 0;
    for (int l = lane; l < len_eff; l += 64) {
        wq[(size_t)l * 5 + k] = __expf(cv[n] - m) * invs * wq[(size_t)l * 5 + 4];
        ++n;
    }
}

// ---------------- accum ----------------
template <typename T>
__device__ void accum_body(const T* probes, const T* gallery, const int* plen,
                           const int* glen, float* wsf) {
    int bx = blockIdx.x, set = bx >> 2, c = bx & 3;
    bool probe = set < NPROBE;
    int L = probe ? LPR : LGA;
    const T* feat = probe ? probes + (size_t)set * L * DIM_
                          : gallery + (size_t)(set - NPROBE) * L * DIM_;
    int len = probe ? plen[set] : glen[set - NPROBE];
    int len_eff = min(max(len, 1), L);
    int r0 = c * (L / 4), r1 = min(r0 + L / 4, len_eff);
    int tid = threadIdx.x, g = tid >> 8, t = tid & 255;
    __shared__ float cf[512];
    __shared__ float pbuf[2048];
    int nr = r1 - r0;
    const float* wq = wsf + F_WQ + (size_t)set * 2560;
    for (int p = tid; p < nr * 4; p += 512)
        cf[p] = wq[(size_t)(r0 + (p >> 2)) * 5 + (p & 3)];
    __syncthreads();
    float ac[8] = {0.f, 0.f, 0.f, 0.f, 0.f, 0.f, 0.f, 0.f};
#pragma unroll 4
    for (int l = r0 + g; l < r1; l += 2) {
        float f0, f1;
        if constexpr (sizeof(T) == 2) {
            unsigned u = *(const unsigned*)((const us*)feat + (size_t)l * DIM_ + t * 2);
            f0 = __uint_as_float(u << 16);
            f1 = __uint_as_float(u & 0xFFFF0000u);
        } else {
            const T* rp = feat + (size_t)l * DIM_ + t * 2;
            f0 = rp[0]; f1 = rp[1];
        }
        f32x4 cc = *(const f32x4*)&cf[(l - r0) * 4];
#pragma unroll
        for (int k = 0; k < 4; ++k) {
            ac[k * 2] += f0 * cc[k];
            ac[k * 2 + 1] += f1 * cc[k];
        }
    }
    if (g == 1) {
#pragma unroll
        for (int i = 0; i < 8; ++i) pbuf[i * 256 + t] = ac[i];
    }
    __syncthreads();
    if (g == 0) {
        float* P = wsf + F_ACC + (size_t)bx * 2048;
#pragma unroll
        for (int k = 0; k < 4; ++k) {
            P[k * 512 + t * 2] = ac[k * 2] + pbuf[(k * 2) * 256 + t];
            P[k * 512 + t * 2 + 1] = ac[k * 2 + 1] + pbuf[(k * 2 + 1) * 256 + t];
        }
    }
}
__global__ __launch_bounds__(512) void accum_kernel(const int* flag, const void* probes,
        const void* gallery, const int* plen, const int* glen, float* wsf) {
    if (*flag) accum_body<us>((const us*)probes, (const us*)gallery, plen, glen, wsf);
    else accum_body<float>((const float*)probes, (const float*)gallery, plen, glen, wsf);
}

// ---------------- reduce ----------------
template <typename T>
__device__ void reduce_body(const float* wsf, T* dout) {
    int set = blockIdx.x, d = threadIdx.x;
    const float* A = wsf + F_ACC + (size_t)set * 4 * 2048;
    size_t ob = (set < NPROBE) ? O_OUT1 + (size_t)set * 2048
                               : O_OUT3 + (size_t)(set - NPROBE) * 2048;
#pragma unroll
    for (int k = 0; k < 4; ++k) {
        float s = A[k * 512 + d] + A[2048 + k * 512 + d] + A[4096 + k * 512 + d] + A[6144 + k * 512 + d];
        stT(dout + ob + k * 512 + d, s);
    }
}
__global__ __launch_bounds__(512) void reduce_kernel(const int* flag, const float* wsf, void* dout) {
    if (*flag) reduce_body<us>(wsf, (us*)dout);
    else reduce_body<float>(wsf, (float*)dout);
}

}  // namespace

extern "C" void kernel_launch(void* const* d_in, const int* in_sizes, int n_in,
                              void* d_out, int out_size, void* d_ws, size_t ws_size,
                              hipStream_t stream) {
    if (ws_size < WS_BYTES) return;
    float* wsf = (float*)d_ws;
    int* flag = (int*)d_ws;
    us* SUMM = (us*)(wsf + F_SUMM);
    us* H1 = (us*)(wsf + F_H1);
    us* H2 = (us*)(wsf + F_H2);
    us* CTXb = (us*)(wsf + F_CTX);
    us* CTXW = (us*)(wsf + F_CTXW);
    us* WT = (us*)(wsf + F_WT);
    const int* plen = (const int*)d_in[2];
    const int* glen = (const int*)d_in[3];

    detect_kernel<<<1, 64, 0, stream>>>((const unsigned int*)d_in[8], flag);
    proxies_kernel<<<22, 64, 0, stream>>>(flag, d_in[4], d_in[5], d_in[6], d_in[7], wsf, d_out);
    wt_kernel<<<dim3(8, 8), 256, 0, stream>>>(flag, d_in[8], WT);
    sums_kernel<<<NSETS * 4, 256, 0, stream>>>(flag, d_in[0], d_in[1], plen, glen, wsf);
    sims_kernel<<<1024, 256, 0, stream>>>(flag, d_in[0], d_in[1], plen, glen, d_in[6], wsf);
    statsfin_kernel<<<NSETS, 256, 0, stream>>>(plen, glen, wsf);

    mlp_one<1024, 1536, 1><<<3 * 16 * KALL, 256, 0, stream>>>(
        flag, d_in[10], d_in[11], d_in[4], d_in[5], SUMM, H1);
    mlp_one<1024, 1024, 0><<<3 * 16 * KALL, 256, 0, stream>>>(
        flag, d_in[12], d_in[13], d_in[4], d_in[5], H1, H2);
    mlp_one<512, 1024, 0><<<3 * 8 * KALL, 256, 0, stream>>>(
        flag, d_in[14], d_in[15], d_in[4], d_in[5], H2, CTXb);

    fold_kernel<<<dim3(8, 22), 256, 0, stream>>>(CTXb, WT, CTXW);
    s0a_kernel<<<528, 256, 0, stream>>>(flag, CTXb, d_in[9], wsf + F_S0A);
    score_kernel<<<1024, 256, 0, stream>>>(flag, d_in[0], d_in[1], plen, glen, wsf);
    softmax_kernel<<<NSETS, 256, 0, stream>>>(plen, glen, wsf);
    accum_kernel<<<NSETS * 4, 512, 0, stream>>>(flag, d_in[0], d_in[1], plen, glen, wsf);
    reduce_kernel<<<NSETS, 512, 0, stream>>>(flag, wsf, d_out);
}

// Round 2
// 415.559 us; speedup vs baseline: 1.0131x; 1.0131x over previous
//
#include <hip/hip_runtime.h>
#include <hip/hip_bf16.h>

namespace {

using us = unsigned short;
typedef __attribute__((ext_vector_type(8))) short bf16x8;
typedef __attribute__((ext_vector_type(4))) float f32x4;
typedef __attribute__((ext_vector_type(4))) unsigned short us4;
typedef __attribute__((ext_vector_type(4))) unsigned int u32x4;

constexpr int DIM_ = 512, KALL = 11, DOM = 10, NPROBE = 128, NSETS = 192;
constexpr int LPR = 256, LGA = 512;

// output offsets (elements)
constexpr size_t O_OUT1 = 0;
constexpr size_t O_OUT2 = (size_t)NPROBE * 4 * DIM_;
constexpr size_t O_OUT3 = O_OUT2 + KALL * DOM;
constexpr size_t O_OUT4 = O_OUT3 + (size_t)64 * 4 * DIM_;

// workspace layout (float units). flag int at [0].
constexpr size_t F_TP   = 64;        // 256 f  normalized proxy transforms
constexpr size_t F_IDX  = 320;       // 768 i  top4 expert ids
constexpr size_t F_S0A  = 1600;      // 2112 f pb.ctx per (e,set)
constexpr size_t F_WQ   = 4096;      // [192][512][5] f32: scores k=0..3, invn at 4
constexpr size_t F_GP   = 495616;    // [1024][12] f32 gsim partials
constexpr size_t F_SUMM = 514048;    // bf16 [192][1024] mean|var
constexpr size_t F_H1   = 612352;    // bf16 [11][192][1024]
constexpr size_t F_PART = F_H1;      // [768][1024] f32 (psum|psq), dies before mlp1
constexpr size_t F_CTXW = F_H1;      // bf16 [11][192][512], after mlp2
constexpr size_t F_H2   = 1693696;   // bf16 [11][192][1024]
constexpr size_t F_ACC  = F_H2;      // [768][2048] f32, after score
constexpr size_t F_CTX  = 2775040;   // bf16 [11][192][512]
constexpr size_t F_WT   = 3315712;   // bf16 [512][512]
constexpr size_t WS_FLOATS = 3446784;
constexpr size_t WS_BYTES  = WS_FLOATS * 4;

__device__ __forceinline__ float b2f(us u) { return __uint_as_float(((unsigned)u) << 16); }
__device__ __forceinline__ us f2b(float x) {
    unsigned u = __float_as_uint(x);
    u += 0x7FFF + ((u >> 16) & 1);
    return (us)(u >> 16);
}
__device__ __forceinline__ float ldT(const float* p) { return *p; }
__device__ __forceinline__ float ldT(const us* p) { return b2f(*p); }
__device__ __forceinline__ void stT(float* p, float v) { *p = v; }
__device__ __forceinline__ void stT(us* p, float v) { *p = f2b(v); }

__device__ __forceinline__ bf16x8 loadA(const us* p) { return *(const bf16x8*)p; }
__device__ __forceinline__ bf16x8 loadA(const float* p) {
    f32x4 a = *(const f32x4*)p, b = *(const f32x4*)(p + 4);
    bf16x8 r;
#pragma unroll
    for (int j = 0; j < 4; ++j) { r[j] = (short)f2b(a[j]); r[4 + j] = (short)f2b(b[j]); }
    return r;
}

__device__ __forceinline__ void gload_lds16(const us* g, us* l) {
    __builtin_amdgcn_global_load_lds(
        (const __attribute__((address_space(1))) void*)g,
        (__attribute__((address_space(3))) void*)l, 16, 0, 0);
}

// decode 64-row-chunk grid (1024 blocks): probe 128x4, gallery 64x8
__device__ __forceinline__ void decode64(int bx, int& set, int& base, int& L) {
    if (bx < 512) { set = bx >> 2; base = (bx & 3) * 64; L = LPR; }
    else { set = NPROBE + ((bx - 512) >> 3); base = ((bx - 512) & 7) * 64; L = LGA; }
}

// ---------------- dtype detector ----------------
__global__ void detect_kernel(const unsigned int* probeW_bits, int* flag) {
    if (threadIdx.x == 0) *flag = (probeW_bits[0] == 0x3F800000u) ? 0 : 1;
}

// ---------------- proxies: out2/out4 + normalized tp ----------------
template <typename T>
__device__ void proxies_body(const T* pp, const T* pg, const T* tW, const T* tb,
                             float* wsf, T* dout) {
    int b = blockIdx.x;
    int fam = b / KALL, i = b % KALL;
    int lane = threadIdx.x;
    const T* src = fam ? pg : pp;
    float t[DOM];
#pragma unroll
    for (int r = 0; r < DOM; ++r) t[r] = 0.f;
    for (int d = lane; d < DIM_; d += 64) {
        float x = ldT(src + (size_t)i * DIM_ + d);
#pragma unroll
        for (int r = 0; r < DOM; ++r) t[r] += x * ldT(tW + (size_t)r * DIM_ + d);
    }
#pragma unroll
    for (int off = 32; off >= 1; off >>= 1)
#pragma unroll
        for (int r = 0; r < DOM; ++r) t[r] += __shfl_xor(t[r], off, 64);
#pragma unroll
    for (int r = 0; r < DOM; ++r) t[r] += ldT(tb + r);
    float nn = 0.f;
#pragma unroll
    for (int r = 0; r < DOM; ++r) nn += t[r] * t[r];
    float inv = 1.0f / fmaxf(sqrtf(nn), 1e-12f);
    if (lane < DOM) {
        size_t base = fam ? O_OUT4 : O_OUT2;
        stT(dout + base + i * DOM + lane, t[lane]);
        wsf[F_TP + fam * 128 + i * DOM + lane] = t[lane] * inv;
    }
}
__global__ void proxies_kernel(const int* flag, const void* pp, const void* pg,
                               const void* tW, const void* tb, float* wsf, void* dout) {
    if (*flag)
        proxies_body<us>((const us*)pp, (const us*)pg, (const us*)tW, (const us*)tb, wsf, (us*)dout);
    else
        proxies_body<float>((const float*)pp, (const float*)pg, (const float*)tW, (const float*)tb, wsf, (float*)dout);
}

// ---------------- pass A: per-dim sums/sumsq (pure column sums, no shuffles) ---
template <typename T>
__device__ void sums_body(const T* probes, const T* gallery, const int* plen,
                          const int* glen, float* wsf) {
    int bx = blockIdx.x, set = bx >> 2, c = bx & 3;
    bool probe = set < NPROBE;
    int L = probe ? LPR : LGA;
    const T* feat = probe ? probes + (size_t)set * L * DIM_
                          : gallery + (size_t)(set - NPROBE) * L * DIM_;
    int len = probe ? plen[set] : glen[set - NPROBE];
    int len_eff = min(max(len, 1), L);
    // dynamic balanced partition of [0, len_eff) into 4 chunks
    int r0 = (c * len_eff) >> 2, r1 = ((c + 1) * len_eff) >> 2;
    __shared__ float psum[DIM_], psq[DIM_];
    int tid = threadIdx.x, w = tid >> 6, lane = tid & 63;
    psum[tid] = 0.f; psum[tid + 256] = 0.f;
    psq[tid] = 0.f; psq[tid + 256] = 0.f;
    __syncthreads();
    float asum[8] = {0,0,0,0,0,0,0,0}, asq[8] = {0,0,0,0,0,0,0,0};
    for (int l = r0 + w * 2; l < r1; l += 8) {
        bool two = (l + 1 < r1);
        float f0[8], f1[8];
        if constexpr (sizeof(T) == 2) {
            u32x4 ra = *(const u32x4*)(feat + (size_t)l * DIM_ + lane * 8);
            u32x4 rb = two ? *(const u32x4*)(feat + (size_t)(l + 1) * DIM_ + lane * 8)
                           : (u32x4){0, 0, 0, 0};
#pragma unroll
            for (int q = 0; q < 4; ++q) {
                f0[2*q] = __uint_as_float(ra[q] << 16);
                f0[2*q+1] = __uint_as_float(ra[q] & 0xFFFF0000u);
                f1[2*q] = __uint_as_float(rb[q] << 16);
                f1[2*q+1] = __uint_as_float(rb[q] & 0xFFFF0000u);
            }
        } else {
            const T* rp = feat + (size_t)l * DIM_ + lane * 8;
            f32x4 a0 = *(const f32x4*)rp, a1 = *(const f32x4*)(rp + 4);
#pragma unroll
            for (int j = 0; j < 4; ++j) { f0[j] = a0[j]; f0[4+j] = a1[j]; }
            if (two) {
                const T* rq = feat + (size_t)(l + 1) * DIM_ + lane * 8;
                f32x4 b0 = *(const f32x4*)rq, b1 = *(const f32x4*)(rq + 4);
#pragma unroll
                for (int j = 0; j < 4; ++j) { f1[j] = b0[j]; f1[4+j] = b1[j]; }
            } else {
#pragma unroll
                for (int j = 0; j < 8; ++j) f1[j] = 0.f;
            }
        }
#pragma unroll
        for (int j = 0; j < 8; ++j) {
            asum[j] += f0[j] + f1[j];
            asq[j] += f0[j] * f0[j] + f1[j] * f1[j];
        }
    }
#pragma unroll
    for (int j = 0; j < 8; ++j) {
        atomicAdd(&psum[lane * 8 + j], asum[j]);
        atomicAdd(&psq[lane * 8 + j], asq[j]);
    }
    __syncthreads();
    float* P = wsf + F_PART + (size_t)bx * 1024;
    P[tid] = psum[tid]; P[tid + 256] = psum[tid + 256];
    P[512 + tid] = psq[tid]; P[768 + tid] = psq[tid + 256];
}
__global__ __launch_bounds__(256) void sums_kernel(const int* flag, const void* probes,
        const void* gallery, const int* plen, const int* glen, float* wsf) {
    if (*flag) sums_body<us>((const us*)probes, (const us*)gallery, plen, glen, wsf);
    else sums_body<float>((const float*)probes, (const float*)gallery, plen, glen, wsf);
}

// ---------------- pass B: gsim via MFMA (feat @ tW^T) + per-row invn ----------
template <typename T>
__device__ void sims_body(const T* probes, const T* gallery, const int* plen,
                          const int* glen, const T* tW, float* wsf) {
    int bx = blockIdx.x, set, base, L;
    decode64(bx, set, base, L);
    bool probe = set < NPROBE;
    int len = probe ? plen[set] : glen[set - NPROBE];
    int len_eff = min(max(len, 1), L);
    float* GP = wsf + F_GP + (size_t)bx * 12;
    int tid = threadIdx.x;
    if (base >= len_eff) { if (tid < KALL) GP[tid] = 0.f; return; }
    const T* feat = probe ? probes + (size_t)set * L * DIM_
                          : gallery + (size_t)(set - NPROBE) * L * DIM_;
    __shared__ __align__(16) float tile[4][320];   // [wave][16 rows][20 cols]
    __shared__ float tpl[KALL * DOM];
    __shared__ float gs[16];
    if (tid < KALL * DOM) tpl[tid] = wsf[F_TP + (probe ? 0 : 128) + tid];
    if (tid < 16) gs[tid] = 0.f;
    int w = tid >> 6, lane = tid & 63, lm = lane & 15, quad = lane >> 4;

    bf16x8 bq[16];
#pragma unroll
    for (int s = 0; s < 16; ++s) {
        if (lm < DOM) bq[s] = loadA(tW + (size_t)lm * DIM_ + s * 32 + quad * 8);
        else bq[s] = (bf16x8){0, 0, 0, 0, 0, 0, 0, 0};
    }
    int m0 = base + w * 16;
    const T* Ap = feat + (size_t)(m0 + lm) * DIM_ + quad * 8;
    f32x4 acc = (f32x4){0.f, 0.f, 0.f, 0.f};
    // per-lane partial sumsq of row m0+lm (this lane covers dims quad*8+s*32+j)
    float vsq = 0.f;
#pragma unroll
    for (int s = 0; s < 16; ++s) {
        bf16x8 a;
        if constexpr (sizeof(T) == 2) {
            a = *(const bf16x8*)(Ap + s * 32);
#pragma unroll
            for (int j = 0; j < 8; ++j) { float x = b2f((us)a[j]); vsq += x * x; }
        } else {
            f32x4 p0 = *(const f32x4*)(Ap + s * 32), p1 = *(const f32x4*)(Ap + s * 32 + 4);
#pragma unroll
            for (int j = 0; j < 4; ++j) {
                vsq += p0[j] * p0[j] + p1[j] * p1[j];
                a[j] = (short)f2b(p0[j]); a[4 + j] = (short)f2b(p1[j]);
            }
        }
        acc = __builtin_amdgcn_mfma_f32_16x16x32_bf16(a, bq[s], acc, 0, 0, 0);
    }
    // reduce sumsq across the 4 quad-lanes holding the same row
    vsq += __shfl_xor(vsq, 16, 64);
    vsq += __shfl_xor(vsq, 32, 64);
    {
        int rown = m0 + lm;
        if (quad == 0 && rown < len_eff)
            wsf[F_WQ + (size_t)set * 2560 + (size_t)rown * 5 + 4] =
                1.0f / fmaxf(sqrtf(vsq), 1e-12f);
    }
#pragma unroll
    for (int r = 0; r < 4; ++r) tile[w][(quad * 4 + r) * 20 + lm] = acc[r];
    __syncthreads();

    float gacc[KALL];
#pragma unroll
    for (int k = 0; k < KALL; ++k) gacc[k] = 0.f;
    if (lane < 16) {
        int row = m0 + lane;
        if (row < len_eff) {
            const float* tr = &tile[w][lane * 20];
            f32x4 t0 = *(const f32x4*)tr, t1 = *(const f32x4*)(tr + 4);
            float tv[DOM] = {t0[0], t0[1], t0[2], t0[3], t1[0], t1[1], t1[2], t1[3], tr[8], tr[9]};
            float nn = 0.f;
#pragma unroll
            for (int r = 0; r < DOM; ++r) nn += tv[r] * tv[r];
            float inv = 1.0f / fmaxf(sqrtf(nn), 1e-12f);
#pragma unroll
            for (int k = 0; k < KALL; ++k) {
                float s = 0.f;
#pragma unroll
                for (int r = 0; r < DOM; ++r) s += tv[r] * tpl[k * DOM + r];
                gacc[k] = s * inv;
            }
        }
    }
#pragma unroll
    for (int off = 8; off >= 1; off >>= 1)
#pragma unroll
        for (int k = 0; k < KALL; ++k) gacc[k] += __shfl_xor(gacc[k], off, 64);
    if (lane == 0)
#pragma unroll
        for (int k = 0; k < KALL; ++k) atomicAdd(&gs[k], gacc[k]);
    __syncthreads();
    if (tid < KALL) GP[tid] = gs[tid];
}
__global__ __launch_bounds__(256, 3) void sims_kernel(const int* flag, const void* probes,
        const void* gallery, const int* plen, const int* glen, const void* tW, float* wsf) {
    if (*flag) sims_body<us>((const us*)probes, (const us*)gallery, plen, glen, (const us*)tW, wsf);
    else sims_body<float>((const float*)probes, (const float*)gallery, plen, glen, (const float*)tW, wsf);
}

// ---------------- finalize stats: SUMM (bf16) + top4 ----------------
__global__ void statsfin_kernel(const int* plen, const int* glen, float* wsf) {
    int set = blockIdx.x, tid = threadIdx.x;
    bool probe = set < NPROBE;
    int len = probe ? plen[set] : glen[set - NPROBE];
    float lp = (float)max(len, 1);
    const float* P = wsf + F_PART + (size_t)set * 4 * 1024;
    us* SUMM = (us*)(wsf + F_SUMM);
    for (int d = tid; d < DIM_; d += 256) {
        float s = P[d] + P[1024 + d] + P[2048 + d] + P[3072 + d];
        float q = P[512 + d] + P[1536 + d] + P[2560 + d] + P[3584 + d];
        float m = s / lp;
        float v = q / lp - m * m;
        SUMM[(size_t)set * 1024 + d] = f2b(m);
        SUMM[(size_t)set * 1024 + DIM_ + d] = f2b(v);
    }
    if (tid == 0) {
        int nch = probe ? 4 : 8;
        int gb = probe ? set * 4 : 512 + (set - NPROBE) * 8;
        float g[KALL];
        for (int i = 0; i < KALL; ++i) {
            float s = 0.f;
            for (int c = 0; c < nch; ++c) s += wsf[F_GP + (size_t)(gb + c) * 12 + i];
            g[i] = s;
        }
        int* idx4 = (int*)(wsf + F_IDX);
        for (int kk = 0; kk < 4; ++kk) {
            int bi = 0; float bv = g[0];
            for (int i = 1; i < KALL; ++i)
                if (g[i] > bv) { bv = g[i]; bi = i; }
            idx4[set * 4 + kk] = bi;
            g[bi] = -3e38f;
        }
    }
}

// ---------------- W transpose -> WT bf16 [j][d] ----------------
template <typename T>
__device__ void wt_body(const T* W, us* WT) {
    __shared__ us t[64][65];
    int bi = blockIdx.y * 64, bj = blockIdx.x * 64, tid = threadIdx.x;
    for (int i = tid; i < 4096; i += 256) {
        int r = i >> 6, cc = i & 63;
        t[r][cc] = (sizeof(T) == 2) ? ((const us*)W)[(size_t)(bi + r) * DIM_ + bj + cc]
                                    : f2b(ldT(W + (size_t)(bi + r) * DIM_ + bj + cc));
    }
    __syncthreads();
    for (int i = tid; i < 4096; i += 256) {
        int r = i >> 6, cc = i & 63;
        WT[(size_t)(bj + r) * DIM_ + bi + cc] = t[cc][r];
    }
}
__global__ void wt_kernel(const int* flag, const void* W, us* WT) {
    if (*flag) wt_body<us>((const us*)W, WT);
    else wt_body<float>((const float*)W, WT);
}

// ---------------- unified LDS-staged MFMA MLP ----------------
// fp32 weights: convert during staging (dwordx4 loads -> pack bf16 -> ds_write_b128).
// bf16 weights: async global_load_lds. Same swizzled layout + MFMA loop for both.
// XCD-aware 1D grid: blocks sharing a W m-tile differ by MT*KALL (== 0 mod 8) -> same XCD.
template <int M, int KTOT, int L1>
__global__ __launch_bounds__(256) void mlp_one(const int* flag, const void* Wv,
        const void* biasv, const void* ppv, const void* pgv, const us* X, us* Y) {
    constexpr int MT = M / 64;
    int flagv = *flag;
    __shared__ us SM[16384];
    us* As = SM;
    us* Bs = SM + 8192;
    int bx = blockIdx.x;
    int nt = bx / (MT * KALL);
    int rem = bx - nt * (MT * KALL);
    int e = rem % KALL;
    int mt = rem / KALL;
    int tid = threadIdx.x, w = tid >> 6, lane = tid & 63;
    int lm = lane & 15, quad = lane >> 4;
    const int RS = L1 ? 1024 : KTOT;
    int s0 = nt * 64;
    int srow = tid >> 4;
    int csrc = (tid & 15) ^ (srow & 7);
    us* lA = As + tid * 8;
    us* lB = Bs + tid * 8;
    const size_t arow = (size_t)e * M + mt * 64 + srow;
    const us*    AbB = (const us*)Wv + arow * KTOT + csrc * 8;
    const float* AbF = (const float*)Wv + arow * KTOT + csrc * 8;
    const us* Xbase = X + ((size_t)(L1 ? 0 : e * NSETS) + s0 + srow) * RS + csrc * 8;
    const us* PbB = nullptr;
    const float* PbF = nullptr;
    if (L1) {
        PbB = (const us*)(nt < 2 ? ppv : pgv) + (size_t)e * DIM_ + csrc * 8;
        PbF = (const float*)(nt < 2 ? ppv : pgv) + (size_t)e * DIM_ + csrc * 8;
    }
    f32x4 acc[4];
#pragma unroll
    for (int j = 0; j < 4; ++j) acc[j] = (f32x4){0.f, 0.f, 0.f, 0.f};
    int ar = w * 16 + lm, aswz = ar & 7;

    for (int k0 = 0; k0 < KTOT; k0 += 128) {
        __syncthreads();
        if (flagv) {
#pragma unroll
            for (int i = 0; i < 4; ++i)
                gload_lds16(AbB + (size_t)(i * 16) * KTOT + k0, lA + i * 2048);
        } else {
#pragma unroll
            for (int i = 0; i < 4; ++i)
                *(bf16x8*)(lA + i * 2048) = loadA(AbF + (size_t)(i * 16) * KTOT + k0);
        }
        if (!L1 || k0 < 1024) {
#pragma unroll
            for (int i = 0; i < 4; ++i)
                gload_lds16(Xbase + (size_t)(i * 16) * RS + k0, lB + i * 2048);
        } else if (flagv) {
#pragma unroll
            for (int i = 0; i < 4; ++i)
                gload_lds16(PbB + (k0 - 1024), lB + i * 2048);
        } else {
            bf16x8 v = loadA(PbF + (k0 - 1024));
#pragma unroll
            for (int i = 0; i < 4; ++i)
                *(bf16x8*)(lB + i * 2048) = v;
        }
        __syncthreads();
#pragma unroll
        for (int ks = 0; ks < 4; ++ks) {
            int cg = ks * 4 + quad;
            bf16x8 a = *(const bf16x8*)(As + ar * 128 + ((cg ^ aswz) * 8));
#pragma unroll
            for (int j = 0; j < 4; ++j) {
                int br = j * 16 + lm;
                bf16x8 b = *(const bf16x8*)(Bs + br * 128 + ((cg ^ (br & 7)) * 8));
                acc[j] = __builtin_amdgcn_mfma_f32_16x16x32_bf16(a, b, acc[j], 0, 0, 0);
            }
        }
    }
    int m0 = mt * 64 + w * 16 + quad * 4;
    float bv[4];
#pragma unroll
    for (int r = 0; r < 4; ++r)
        bv[r] = flagv ? b2f(((const us*)biasv)[(size_t)e * M + m0 + r])
                      : ((const float*)biasv)[(size_t)e * M + m0 + r];
#pragma unroll
    for (int j = 0; j < 4; ++j) {
        int s = s0 + j * 16 + lm;
        us4 pk;
#pragma unroll
        for (int r = 0; r < 4; ++r) {
            float v = acc[j][r] + bv[r];
            v = v > 0.f ? v : 0.01f * v;
            pk[r] = f2b(v);
        }
        *(us4*)(Y + ((size_t)e * NSETS + s) * M + m0) = pk;
    }
}

// ---------------- fold: CTXW = CTX @ W (probe rows) ----------------
__global__ void fold_kernel(const us* CTX, const us* WT, us* CTXW) {
    int nt = blockIdx.x, mtb = blockIdx.y;
    int e = mtb >> 1, sub = mtb & 1;
    int row0 = e * NSETS + sub * 64;
    int tid = threadIdx.x, w = tid >> 6, lane = tid & 63;
    int lm = lane & 15, quad = lane >> 4, kq = quad * 8;
    const us* Ap = CTX + ((size_t)row0 + w * 16 + lm) * DIM_ + kq;
    int n0 = nt * 64;
    const us* Bp = WT + (size_t)(n0 + lm) * DIM_ + kq;
    f32x4 acc[4];
#pragma unroll
    for (int j = 0; j < 4; ++j) acc[j] = (f32x4){0.f, 0.f, 0.f, 0.f};
#pragma unroll 2
    for (int kc = 0; kc < DIM_; kc += 32) {
        bf16x8 a = *(const bf16x8*)(Ap + kc);
#pragma unroll
        for (int j = 0; j < 4; ++j) {
            bf16x8 b = *(const bf16x8*)(Bp + kc + (size_t)j * 16 * DIM_);
            acc[j] = __builtin_amdgcn_mfma_f32_16x16x32_bf16(a, b, acc[j], 0, 0, 0);
        }
    }
    int mrow = row0 + w * 16 + quad * 4;
#pragma unroll
    for (int j = 0; j < 4; ++j)
#pragma unroll
        for (int r = 0; r < 4; ++r)
            CTXW[(size_t)(mrow + r) * DIM_ + n0 + j * 16 + lm] = f2b(acc[j][r]);
}

// ---------------- s0 = pb . ctx ----------------
template <typename T>
__device__ void s0a_body(const us* CTX, const T* pb, float* S0A) {
    int tid = threadIdx.x, w = tid >> 6, lane = tid & 63;
    int row = blockIdx.x * 4 + w;
    bf16x8 cv = *(const bf16x8*)(CTX + (size_t)row * DIM_ + lane * 8);
    float s = 0.f;
#pragma unroll
    for (int j = 0; j < 8; ++j) s += b2f((us)cv[j]) * ldT(pb + lane * 8 + j);
#pragma unroll
    for (int off = 32; off >= 1; off >>= 1) s += __shfl_xor(s, off, 64);
    if (lane == 0) S0A[row] = s;
}
__global__ void s0a_kernel(const int* flag, const us* CTX, const void* pb, float* S0A) {
    if (*flag) s0a_body<us>(CTX, (const us*)pb, S0A);
    else s0a_body<float>(CTX, (const float*)pb, S0A);
}

// ---------------- score: feat @ ctx^T via MFMA ----------------
template <typename T>
__device__ void score_body(const T* probes, const T* gallery, const int* plen,
                           const int* glen, float* wsf) {
    int bx = blockIdx.x, set, base, L;
    decode64(bx, set, base, L);
    bool probe = set < NPROBE;
    int len = probe ? plen[set] : glen[set - NPROBE];
    int len_eff = min(max(len, 1), L);
    if (base >= len_eff) return;
    const T* feat = probe ? probes + (size_t)set * L * DIM_
                          : gallery + (size_t)(set - NPROBE) * L * DIM_;
    int tid = threadIdx.x, w = tid >> 6, lane = tid & 63;
    int lm = lane & 15, quad = lane >> 4;
    const int* idx4 = (const int*)(wsf + F_IDX);
    const us* CTXW = (const us*)(wsf + F_CTXW);
    const us* CTXR = (const us*)(wsf + F_CTX);
    bf16x8 bq[16];
    float s0v = 0.f;
    if (lm < 4) {
        int row = idx4[set * 4 + lm] * NSETS + set;
        const us* src = (probe ? CTXW : CTXR) + (size_t)row * DIM_ + quad * 8;
#pragma unroll
        for (int s = 0; s < 16; ++s) bq[s] = *(const bf16x8*)(src + s * 32);
        s0v = probe ? wsf[F_S0A + row] : 0.f;
    } else {
#pragma unroll
        for (int s = 0; s < 16; ++s) bq[s] = (bf16x8){0, 0, 0, 0, 0, 0, 0, 0};
    }
    int m0 = base + w * 16;
    const T* Ap = feat + (size_t)(m0 + lm) * DIM_ + quad * 8;
    f32x4 acc = (f32x4){0.f, 0.f, 0.f, 0.f};
#pragma unroll
    for (int s = 0; s < 16; ++s) {
        bf16x8 a = loadA(Ap + s * 32);
        acc = __builtin_amdgcn_mfma_f32_16x16x32_bf16(a, bq[s], acc, 0, 0, 0);
    }
    if (lm < 4) {
        float* wq = wsf + F_WQ + (size_t)set * 2560;
#pragma unroll
        for (int r = 0; r < 4; ++r) {
            int row = m0 + quad * 4 + r;
            wq[(size_t)row * 5 + lm] = acc[r] + s0v;
        }
    }
}
__global__ __launch_bounds__(256, 3) void score_kernel(const int* flag, const void* probes,
        const void* gallery, const int* plen, const int* glen, float* wsf) {
    if (*flag) score_body<us>((const us*)probes, (const us*)gallery, plen, glen, wsf);
    else score_body<float>((const float*)probes, (const float*)gallery, plen, glen, wsf);
}

// ---------------- softmax over rows per (set,k), fold invn ----------------
__global__ void softmax_kernel(const int* plen, const int* glen, float* wsf) {
    int set = blockIdx.x, tid = threadIdx.x, k = tid >> 6, lane = tid & 63;
    bool probe = set < NPROBE;
    int L = probe ? LPR : LGA;
    int len = probe ? plen[set] : glen[set - NPROBE];
    int len_eff = min(max(len, 1), L);
    float* wq = wsf + F_WQ + (size_t)set * 2560;
    float cv[8];
    int n = 0;
    float m = -3e38f;
    for (int l = lane; l < len_eff; l += 64) {
        cv[n] = wq[(size_t)l * 5 + k];
        m = fmaxf(m, cv[n]);
        ++n;
    }
#pragma unroll
    for (int off = 32; off >= 1; off >>= 1) m = fmaxf(m, __shfl_xor(m, off, 64));
    float se = 0.f;
    for (int i = 0; i < n; ++i) se += __expf(cv[i] - m);
#pragma unroll
    for (int off = 32; off >= 1; off >>= 1) se += __shfl_xor(se, off, 64);
    float invs = 1.0f / se;
    n = 0;
    for (int l = lane; l < len_eff; l += 64) {
        wq[(size_t)l * 5 + k] = __expf(cv[n] - m) * invs * wq[(size_t)l * 5 + 4];
        ++n;
    }
}

// ---------------- accum ----------------
template <typename T>
__device__ void accum_body(const T* probes, const T* gallery, const int* plen,
                           const int* glen, float* wsf) {
    int bx = blockIdx.x, set = bx >> 2, c = bx & 3;
    bool probe = set < NPROBE;
    int L = probe ? LPR : LGA;
    const T* feat = probe ? probes + (size_t)set * L * DIM_
                          : gallery + (size_t)(set - NPROBE) * L * DIM_;
    int len = probe ? plen[set] : glen[set - NPROBE];
    int len_eff = min(max(len, 1), L);
    // dynamic balanced partition of [0, len_eff) into 4 chunks
    int r0 = (c * len_eff) >> 2, r1 = ((c + 1) * len_eff) >> 2;
    int tid = threadIdx.x, g = tid >> 8, t = tid & 255;
    __shared__ float cf[512];
    __shared__ float pbuf[2048];
    int nr = r1 - r0;
    const float* wq = wsf + F_WQ + (size_t)set * 2560;
    for (int p = tid; p < nr * 4; p += 512)
        cf[p] = wq[(size_t)(r0 + (p >> 2)) * 5 + (p & 3)];
    __syncthreads();
    float ac[8] = {0.f, 0.f, 0.f, 0.f, 0.f, 0.f, 0.f, 0.f};
#pragma unroll 4
    for (int l = r0 + g; l < r1; l += 2) {
        float f0, f1;
        if constexpr (sizeof(T) == 2) {
            unsigned u = *(const unsigned*)((const us*)feat + (size_t)l * DIM_ + t * 2);
            f0 = __uint_as_float(u << 16);
            f1 = __uint_as_float(u & 0xFFFF0000u);
        } else {
            const T* rp = feat + (size_t)l * DIM_ + t * 2;
            f0 = rp[0]; f1 = rp[1];
        }
        f32x4 cc = *(const f32x4*)&cf[(l - r0) * 4];
#pragma unroll
        for (int k = 0; k < 4; ++k) {
            ac[k * 2] += f0 * cc[k];
            ac[k * 2 + 1] += f1 * cc[k];
        }
    }
    if (g == 1) {
#pragma unroll
        for (int i = 0; i < 8; ++i) pbuf[i * 256 + t] = ac[i];
    }
    __syncthreads();
    if (g == 0) {
        float* P = wsf + F_ACC + (size_t)bx * 2048;
#pragma unroll
        for (int k = 0; k < 4; ++k) {
            P[k * 512 + t * 2] = ac[k * 2] + pbuf[(k * 2) * 256 + t];
            P[k * 512 + t * 2 + 1] = ac[k * 2 + 1] + pbuf[(k * 2 + 1) * 256 + t];
        }
    }
}
__global__ __launch_bounds__(512) void accum_kernel(const int* flag, const void* probes,
        const void* gallery, const int* plen, const int* glen, float* wsf) {
    if (*flag) accum_body<us>((const us*)probes, (const us*)gallery, plen, glen, wsf);
    else accum_body<float>((const float*)probes, (const float*)gallery, plen, glen, wsf);
}

// ---------------- reduce ----------------
template <typename T>
__device__ void reduce_body(const float* wsf, T* dout) {
    int set = blockIdx.x, d = threadIdx.x;
    const float* A = wsf + F_ACC + (size_t)set * 4 * 2048;
    size_t ob = (set < NPROBE) ? O_OUT1 + (size_t)set * 2048
                               : O_OUT3 + (size_t)(set - NPROBE) * 2048;
#pragma unroll
    for (int k = 0; k < 4; ++k) {
        float s = A[k * 512 + d] + A[2048 + k * 512 + d] + A[4096 + k * 512 + d] + A[6144 + k * 512 + d];
        stT(dout + ob + k * 512 + d, s);
    }
}
__global__ __launch_bounds__(512) void reduce_kernel(const int* flag, const float* wsf, void* dout) {
    if (*flag) reduce_body<us>(wsf, (us*)dout);
    else reduce_body<float>(wsf, (float*)dout);
}

}  // namespace

extern "C" void kernel_launch(void* const* d_in, const int* in_sizes, int n_in,
                              void* d_out, int out_size, void* d_ws, size_t ws_size,
                              hipStream_t stream) {
    if (ws_size < WS_BYTES) return;
    float* wsf = (float*)d_ws;
    int* flag = (int*)d_ws;
    us* SUMM = (us*)(wsf + F_SUMM);
    us* H1 = (us*)(wsf + F_H1);
    us* H2 = (us*)(wsf + F_H2);
    us* CTXb = (us*)(wsf + F_CTX);
    us* CTXW = (us*)(wsf + F_CTXW);
    us* WT = (us*)(wsf + F_WT);
    const int* plen = (const int*)d_in[2];
    const int* glen = (const int*)d_in[3];

    detect_kernel<<<1, 64, 0, stream>>>((const unsigned int*)d_in[8], flag);
    proxies_kernel<<<22, 64, 0, stream>>>(flag, d_in[4], d_in[5], d_in[6], d_in[7], wsf, d_out);
    wt_kernel<<<dim3(8, 8), 256, 0, stream>>>(flag, d_in[8], WT);
    sums_kernel<<<NSETS * 4, 256, 0, stream>>>(flag, d_in[0], d_in[1], plen, glen, wsf);
    sims_kernel<<<1024, 256, 0, stream>>>(flag, d_in[0], d_in[1], plen, glen, d_in[6], wsf);
    statsfin_kernel<<<NSETS, 256, 0, stream>>>(plen, glen, wsf);

    mlp_one<1024, 1536, 1><<<3 * 16 * KALL, 256, 0, stream>>>(
        flag, d_in[10], d_in[11], d_in[4], d_in[5], SUMM, H1);
    mlp_one<1024, 1024, 0><<<3 * 16 * KALL, 256, 0, stream>>>(
        flag, d_in[12], d_in[13], d_in[4], d_in[5], H1, H2);
    mlp_one<512, 1024, 0><<<3 * 8 * KALL, 256, 0, stream>>>(
        flag, d_in[14], d_in[15], d_in[4], d_in[5], H2, CTXb);

    fold_kernel<<<dim3(8, 22), 256, 0, stream>>>(CTXb, WT, CTXW);
    s0a_kernel<<<528, 256, 0, stream>>>(flag, CTXb, d_in[9], wsf + F_S0A);
    score_kernel<<<1024, 256, 0, stream>>>(flag, d_in[0], d_in[1], plen, glen, wsf);
    softmax_kernel<<<NSETS, 256, 0, stream>>>(plen, glen, wsf);
    accum_kernel<<<NSETS * 4, 512, 0, stream>>>(flag, d_in[0], d_in[1], plen, glen, wsf);
    reduce_kernel<<<NSETS, 512, 0, stream>>>(flag, wsf, d_out);
}